// Round 2
// baseline (282.870 us; speedup 1.0000x reference)
//
#include <hip/hip_runtime.h>

#define DEVI __device__ __forceinline__

typedef float f32x4 __attribute__((ext_vector_type(4)));
typedef unsigned int u32x4 __attribute__((ext_vector_type(4)));
typedef __bf16 bf16x8 __attribute__((ext_vector_type(8)));

#define NB 4
#define CIN 256
#define CI_ 128
#define NN 4096
#define SCALE 0.08838834764831845f

DEVI unsigned short f2bf(float f) {
  unsigned int x = __float_as_uint(f);
  x += 0x7FFFu + ((x >> 16) & 1u);
  return (unsigned short)(x >> 16);
}

DEVI f32x4 mfma16(u32x4 a, u32x4 b, f32x4 c) {
  return __builtin_amdgcn_mfma_f32_16x16x32_bf16(
      __builtin_bit_cast(bf16x8, a), __builtin_bit_cast(bf16x8, b), c, 0, 0, 0);
}

DEVI u32x4 pack8(f32x4 a, f32x4 b) {
  u32x4 r;
  r[0] = (unsigned)f2bf(a[0]) | ((unsigned)f2bf(a[1]) << 16);
  r[1] = (unsigned)f2bf(a[2]) | ((unsigned)f2bf(a[3]) << 16);
  r[2] = (unsigned)f2bf(b[0]) | ((unsigned)f2bf(b[1]) << 16);
  r[3] = (unsigned)f2bf(b[2]) | ((unsigned)f2bf(b[3]) << 16);
  return r;
}

DEVI void gload16(const void* g, void* l) {
  __builtin_amdgcn_global_load_lds(
      (const __attribute__((address_space(1))) void*)g,
      (__attribute__((address_space(3))) void*)l, 16, 0, 0);
}

// ---------------- Kernel A: 5 projection GEMMs ----------------
// hqT,hkT,thT,phT stored [b][n][ci] bf16 ; g stored [b][ci][n] bf16
__global__ __launch_bounds__(256) void proj_kernel(
    const float* __restrict__ feats, const float* __restrict__ human,
    const float* __restrict__ g_w, const float* __restrict__ g_b,
    const float* __restrict__ th_w, const float* __restrict__ th_b,
    const float* __restrict__ ph_w, const float* __restrict__ ph_b,
    const float* __restrict__ hth_w, const float* __restrict__ hth_b,
    const float* __restrict__ hph_w, const float* __restrict__ hph_b,
    unsigned short* __restrict__ hqT, unsigned short* __restrict__ hkT,
    unsigned short* __restrict__ thT, unsigned short* __restrict__ phT,
    unsigned short* __restrict__ gP) {
  // LDS x-tiles: [64 n][256 c] bf16, elem swizzle: c ^ ((n&15)<<3)
  __shared__ alignas(16) unsigned short xf[64 * 256];
  __shared__ alignas(16) unsigned short xh[64 * 256];
  const int t = threadIdx.x;
  const int b = blockIdx.y;
  const int n0 = blockIdx.x * 64;
  const int w = t >> 6, l = t & 63, g16 = l >> 4, l15 = l & 15;

  for (int which = 0; which < 2; ++which) {
    const float* src = which ? human : feats;
    unsigned short* dst = which ? xh : xf;
    for (int i = 0; i < 16; ++i) {
      int e = (i * 256 + t) * 4;
      int c = e >> 6, nn = e & 63;
      f32x4 v = *(const f32x4*)(src + (size_t)(b * CIN + c) * NN + n0 + nn);
#pragma unroll
      for (int j = 0; j < 4; ++j) {
        int row = nn + j;
        dst[row * 256 + (c ^ ((row & 15) << 3))] = f2bf(v[j]);
      }
    }
  }
  __syncthreads();

  const float* pw[4] = {hth_w, hph_w, th_w, ph_w};
  const float* pb[4] = {hth_b, hph_b, th_b, ph_b};
  unsigned short* pout[4] = {hqT, hkT, thT, phT};

  // Transposed projections: M = n (rows), N = ci, K = c
  u32x4 afrag[8];
  const int arow = w * 16 + l15;
  for (int p = 0; p < 4; ++p) {
    const unsigned short* tile = (p < 2) ? xh : xf;
    if (p == 0 || p == 2) {
#pragma unroll
      for (int s = 0; s < 8; ++s)
        afrag[s] = *(const u32x4*)((const char*)tile + arow * 512 +
                                   (((s << 6) | (g16 << 4)) ^ (l15 << 4)));
    }
    for (int nt = 0; nt < 8; ++nt) {
      int ci0 = nt * 16;
      const float* wrow = pw[p] + (size_t)(ci0 + l15) * 256;
      f32x4 acc = {0.f, 0.f, 0.f, 0.f};
#pragma unroll
      for (int s = 0; s < 8; ++s) {
        const float* bp = wrow + s * 32 + g16 * 8;
        u32x4 bf = pack8(*(const f32x4*)bp, *(const f32x4*)(bp + 4));
        acc = mfma16(afrag[s], bf, acc);
      }
      float bias = pb[p][ci0 + l15];
#pragma unroll
      for (int r = 0; r < 4; ++r) {
        int nrow = n0 + w * 16 + g16 * 4 + r;
        pout[p][((size_t)b * NN + nrow) * CI_ + ci0 + l15] = f2bf(acc[r] + bias);
      }
    }
  }

  // g projection: M = ci, N = n, K = c  (B-frags straight from global feats)
  for (int mt = 0; mt < 2; ++mt) {
    int cib = w * 32 + mt * 16;
    u32x4 ag[8];
#pragma unroll
    for (int s = 0; s < 8; ++s) {
      const float* ap = g_w + (size_t)(cib + l15) * 256 + s * 32 + g16 * 8;
      ag[s] = pack8(*(const f32x4*)ap, *(const f32x4*)(ap + 4));
    }
    float gb[4];
#pragma unroll
    for (int r = 0; r < 4; ++r) gb[r] = g_b[cib + g16 * 4 + r];
    for (int nt = 0; nt < 4; ++nt) {
      f32x4 acc = {0.f, 0.f, 0.f, 0.f};
#pragma unroll
      for (int s = 0; s < 8; ++s) {
        const float* bp = feats + ((size_t)b * CIN + s * 32 + g16 * 8) * NN +
                          n0 + nt * 16 + l15;
        u32x4 bf;
#pragma unroll
        for (int pp = 0; pp < 4; ++pp) {
          unsigned lo = f2bf(bp[(2 * pp) * NN]);
          unsigned hi = f2bf(bp[(2 * pp + 1) * NN]);
          bf[pp] = lo | (hi << 16);
        }
        acc = mfma16(ag[s], bf, acc);
      }
#pragma unroll
      for (int r = 0; r < 4; ++r) {
        int ci = cib + g16 * 4 + r;
        gP[((size_t)b * CI_ + ci) * NN + n0 + nt * 16 + l15] = f2bf(acc[r] + gb[r]);
      }
    }
  }
}

// ---------------- Kernel B: dual-path flash attention ----------------
__global__ __launch_bounds__(256, 2) void attn_kernel(
    const unsigned short* __restrict__ hqT, const unsigned short* __restrict__ hkT,
    const unsigned short* __restrict__ thT, const unsigned short* __restrict__ phT,
    const unsigned short* __restrict__ gP, unsigned short* __restrict__ yT) {
  __shared__ alignas(16) unsigned short sKh[64 * 128];  // [key][d] swz ((key&7)<<4) bytes
  __shared__ alignas(16) unsigned short sKf[64 * 128];
  __shared__ alignas(16) unsigned short sV[128 * 64];   // [dd][key] swz ((dd&7)<<4)
  __shared__ alignas(16) unsigned short sP[4][2][16 * 64];  // per wave,path [q][key]

  const int t = threadIdx.x, w = t >> 6, l = t & 63, g16 = l >> 4, l15 = l & 15;
  const int b = blockIdx.y, q0 = blockIdx.x * 64;

  u32x4 aQ[2][4];
  {
    const unsigned short* qsrc[2] = {hqT, thT};
    int qrow = q0 + w * 16 + l15;
#pragma unroll
    for (int p = 0; p < 2; ++p)
#pragma unroll
      for (int s = 0; s < 4; ++s)
        aQ[p][s] = *(const u32x4*)(qsrc[p] + ((size_t)b * NN + qrow) * CI_ +
                                   s * 32 + g16 * 8);
  }

  f32x4 Y[2][8];
  float lsum[2][4];
#pragma unroll
  for (int p = 0; p < 2; ++p) {
#pragma unroll
    for (int dt = 0; dt < 8; ++dt) Y[p][dt] = {0.f, 0.f, 0.f, 0.f};
#pragma unroll
    for (int r = 0; r < 4; ++r) lsum[p][r] = 0.f;
  }

  for (int kt = 0; kt < 64; ++kt) {
    const int k0 = kt * 64;
    // ---- stage K (both paths) + V via global_load_lds (pre-swizzled source)
#pragma unroll
    for (int i = 0; i < 4; ++i) {
      int ii = w * 4 + i;
      int keyl = ii * 4 + (l >> 4);
      int sw = ((l & 15) * 16) ^ ((keyl & 7) << 4);
      size_t rowb = ((size_t)b * NN + k0 + keyl) * CI_ * 2;
      gload16((const char*)hkT + rowb + sw, (char*)sKh + ii * 1024);
      gload16((const char*)phT + rowb + sw, (char*)sKf + ii * 1024);
      int cil = ii * 8 + (l >> 3);
      int sw2 = ((l & 7) * 16) ^ ((cil & 7) << 4);
      gload16((const char*)gP + (((size_t)b * CI_ + cil) * NN + k0) * 2 + sw2,
              (char*)sV + ii * 1024);
    }
    __syncthreads();

    // ---- QK^T + exp, both paths, P -> LDS
#pragma unroll
    for (int p = 0; p < 2; ++p) {
      const unsigned short* Kt = p ? sKf : sKh;
#pragma unroll
      for (int nt = 0; nt < 4; ++nt) {
        f32x4 acc = {0.f, 0.f, 0.f, 0.f};
        const char* kbase = (const char*)Kt + (nt * 16 + l15) * 256;
#pragma unroll
        for (int s = 0; s < 4; ++s) {
          u32x4 bk = *(const u32x4*)(kbase +
                                     (((s << 6) | (g16 << 4)) ^ ((l15 & 7) << 4)));
          acc = mfma16(aQ[p][s], bk, acc);
        }
#pragma unroll
        for (int r = 0; r < 4; ++r) {
          float pv = __expf(acc[r] * SCALE);
          lsum[p][r] += pv;
          int qr = g16 * 4 + r;
          sP[w][p][qr * 64 + ((nt * 16 + l15) ^ ((qr & 7) << 3))] = f2bf(pv);
        }
      }
    }
    // ---- P A-frags (same-wave LDS RAW; compiler inserts lgkmcnt)
    u32x4 aP[2][2];
#pragma unroll
    for (int p = 0; p < 2; ++p)
#pragma unroll
      for (int s2 = 0; s2 < 2; ++s2)
        aP[p][s2] = *(const u32x4*)((const char*)sP[w][p] + l15 * 128 +
                                    (((s2 << 6) | (g16 << 4)) ^ ((l15 & 7) << 4)));
    // ---- PV, V-frags shared across both paths
#pragma unroll
    for (int dt = 0; dt < 8; ++dt) {
      const char* vbase = (const char*)sV + (dt * 16 + l15) * 128;
      int sw = (l15 & 7) << 4;
      u32x4 bv0 = *(const u32x4*)(vbase + ((g16 << 4) ^ sw));
      u32x4 bv1 = *(const u32x4*)(vbase + ((64 | (g16 << 4)) ^ sw));
      Y[0][dt] = mfma16(aP[0][0], bv0, Y[0][dt]);
      Y[0][dt] = mfma16(aP[0][1], bv1, Y[0][dt]);
      Y[1][dt] = mfma16(aP[1][0], bv0, Y[1][dt]);
      Y[1][dt] = mfma16(aP[1][1], bv1, Y[1][dt]);
    }
    __syncthreads();
  }

  // ---- finalize: row sums live across the 16 lanes of each l>>4 group
#pragma unroll
  for (int p = 0; p < 2; ++p)
#pragma unroll
    for (int r = 0; r < 4; ++r) {
      float v = lsum[p][r];
      v += __shfl_xor(v, 1);
      v += __shfl_xor(v, 2);
      v += __shfl_xor(v, 4);
      v += __shfl_xor(v, 8);
      lsum[p][r] = v;
    }
#pragma unroll
  for (int dt = 0; dt < 8; ++dt)
#pragma unroll
    for (int r = 0; r < 4; ++r) {
      float yv = 0.5f * (Y[0][dt][r] / lsum[0][r] + Y[1][dt][r] / lsum[1][r]);
      int qrow = q0 + w * 16 + g16 * 4 + r;
      yT[((size_t)b * NN + qrow) * CI_ + dt * 16 + l15] = f2bf(yv);
    }
}

// ---------------- Kernel C: W conv + BN ----------------
__global__ __launch_bounds__(256) void wout_kernel(
    const unsigned short* __restrict__ yT, const float* __restrict__ Ww,
    const float* __restrict__ Wb, const float* __restrict__ gamma,
    const float* __restrict__ beta, const float* __restrict__ mean,
    const float* __restrict__ var, float* __restrict__ out) {
  __shared__ alignas(16) unsigned short sY[64 * 128];  // [n][ci] swz ((n&7)<<4)
  const int t = threadIdx.x, w = t >> 6, l = t & 63, g16 = l >> 4, l15 = l & 15;
  const int n0 = blockIdx.x * 64;
  const int ob = blockIdx.y * 64;
  const int b = blockIdx.z;

#pragma unroll
  for (int i = 0; i < 4; ++i) {
    int ii = w * 4 + i;
    int nl = ii * 4 + (l >> 4);
    int sw = ((l & 15) * 16) ^ ((nl & 7) << 4);
    gload16((const char*)yT + ((size_t)b * NN + n0 + nl) * CI_ * 2 + sw,
            (char*)sY + ii * 1024);
  }
  u32x4 aW[4];
  int orow = ob + w * 16 + l15;
#pragma unroll
  for (int s = 0; s < 4; ++s) {
    const float* ap = Ww + (size_t)orow * CI_ + s * 32 + g16 * 8;
    aW[s] = pack8(*(const f32x4*)ap, *(const f32x4*)(ap + 4));
  }
  float wb[4], inv[4], mu[4], bt[4];
#pragma unroll
  for (int r = 0; r < 4; ++r) {
    int o = ob + w * 16 + g16 * 4 + r;
    wb[r] = Wb[o];
    inv[r] = gamma[o] * rsqrtf(var[o] + 1e-5f);
    mu[r] = mean[o];
    bt[r] = beta[o];
  }
  __syncthreads();

  for (int nt = 0; nt < 4; ++nt) {
    f32x4 acc = {0.f, 0.f, 0.f, 0.f};
    const char* ybase = (const char*)sY + (nt * 16 + l15) * 256;
#pragma unroll
    for (int s = 0; s < 4; ++s) {
      u32x4 bf = *(const u32x4*)(ybase +
                                 (((s << 6) | (g16 << 4)) ^ ((l15 & 7) << 4)));
      acc = mfma16(aW[s], bf, acc);
    }
#pragma unroll
    for (int r = 0; r < 4; ++r) {
      int o = ob + w * 16 + g16 * 4 + r;
      out[((size_t)b * CIN + o) * NN + n0 + nt * 16 + l15] =
          (acc[r] + wb[r] - mu[r]) * inv[r] + bt[r];
    }
  }
}

extern "C" void kernel_launch(void* const* d_in, const int* in_sizes, int n_in,
                              void* d_out, int out_size, void* d_ws, size_t ws_size,
                              hipStream_t stream) {
  const float* feats = (const float*)d_in[0];
  const float* human = (const float*)d_in[1];
  const float* g_w = (const float*)d_in[2];
  const float* g_b = (const float*)d_in[3];
  const float* th_w = (const float*)d_in[4];
  const float* th_b = (const float*)d_in[5];
  const float* ph_w = (const float*)d_in[6];
  const float* ph_b = (const float*)d_in[7];
  const float* hth_w = (const float*)d_in[8];
  const float* hth_b = (const float*)d_in[9];
  const float* hph_w = (const float*)d_in[10];
  const float* hph_b = (const float*)d_in[11];
  const float* Ww = (const float*)d_in[12];
  const float* Wb = (const float*)d_in[13];
  const float* gamma = (const float*)d_in[14];
  const float* beta = (const float*)d_in[15];
  const float* mean = (const float*)d_in[16];
  const float* var = (const float*)d_in[17];

  unsigned short* ws = (unsigned short*)d_ws;
  const size_t SZ = (size_t)NB * NN * CI_;  // 2M elems per projection
  unsigned short* hqT = ws;
  unsigned short* hkT = ws + SZ;
  unsigned short* thT = ws + 2 * SZ;
  unsigned short* phT = ws + 3 * SZ;
  unsigned short* gP = ws + 4 * SZ;
  unsigned short* yT = ws + 5 * SZ;

  proj_kernel<<<dim3(64, 4), 256, 0, stream>>>(feats, human, g_w, g_b, th_w,
                                               th_b, ph_w, ph_b, hth_w, hth_b,
                                               hph_w, hph_b, hqT, hkT, thT, phT,
                                               gP);
  attn_kernel<<<dim3(64, 4), 256, 0, stream>>>(hqT, hkT, thT, phT, gP, yT);
  wout_kernel<<<dim3(64, 4, 4), 256, 0, stream>>>(yT, Ww, Wb, gamma, beta, mean,
                                                  var, (float*)d_out);
}

// Round 3
// 157.214 us; speedup vs baseline: 1.7993x; 1.7993x over previous
//
#include <hip/hip_runtime.h>

#define DEVI __device__ __forceinline__

typedef float f32x4 __attribute__((ext_vector_type(4)));
typedef unsigned int u32x4 __attribute__((ext_vector_type(4)));
typedef unsigned int u32x2 __attribute__((ext_vector_type(2)));
typedef __bf16 bf16x8 __attribute__((ext_vector_type(8)));

#define NB 4
#define CIN 256
#define CI_ 128
#define NN 4096
#define SCALE 0.08838834764831845f

typedef unsigned short us;

DEVI us f2bf(float f) {
  unsigned int x = __float_as_uint(f);
  x += 0x7FFFu + ((x >> 16) & 1u);
  return (us)(x >> 16);
}

DEVI unsigned pack2(float a, float b) {
  return (unsigned)f2bf(a) | ((unsigned)f2bf(b) << 16);
}

DEVI f32x4 mfma16(u32x4 a, u32x4 b, f32x4 c) {
  return __builtin_amdgcn_mfma_f32_16x16x32_bf16(
      __builtin_bit_cast(bf16x8, a), __builtin_bit_cast(bf16x8, b), c, 0, 0, 0);
}

DEVI void gload16(const void* g, void* l) {
  __builtin_amdgcn_global_load_lds(
      (const __attribute__((address_space(1))) void*)g,
      (__attribute__((address_space(3))) void*)l, 16, 0, 0);
}

// ---------------- Kernel 0: weight f32 -> bf16 pre-cast ----------------
// wb layout: [6][32768]: hth, hph, th, ph, g, Ww
__global__ __launch_bounds__(256) void wcvt_kernel(
    const float* __restrict__ hth_w, const float* __restrict__ hph_w,
    const float* __restrict__ th_w, const float* __restrict__ ph_w,
    const float* __restrict__ g_w, const float* __restrict__ Ww,
    us* __restrict__ wb) {
  const float* srcs[6] = {hth_w, hph_w, th_w, ph_w, g_w, Ww};
  const float* s = srcs[blockIdx.y];
  us* d = wb + blockIdx.y * 32768;
  int idx = (blockIdx.x * 256 + threadIdx.x) * 4;
  f32x4 v = *(const f32x4*)(s + idx);
  u32x2 o;
  o[0] = pack2(v[0], v[1]);
  o[1] = pack2(v[2], v[3]);
  *(u32x2*)(d + idx) = o;
}

// ---------------- Kernel A: 5 projection GEMMs ----------------
// hqT,hkT,thT,phT stored [b][n][ci] bf16 ; g stored [b][ci][n] bf16
__global__ __launch_bounds__(256) void proj_kernel(
    const float* __restrict__ feats, const float* __restrict__ human,
    const float* __restrict__ g_b, const float* __restrict__ th_b,
    const float* __restrict__ ph_b, const float* __restrict__ hth_b,
    const float* __restrict__ hph_b, const us* __restrict__ wb,
    us* __restrict__ hqT, us* __restrict__ hkT,
    us* __restrict__ thT, us* __restrict__ phT, us* __restrict__ gP) {
  // LDS x-tiles: [64 n][256 c] bf16, elem swizzle: c ^ ((n&15)<<3)
  __shared__ alignas(16) us xf[64 * 256];
  __shared__ alignas(16) us xh[64 * 256];
  const int t = threadIdx.x;
  const int b = blockIdx.y;
  const int n0 = blockIdx.x * 64;
  const int w = t >> 6, l = t & 63, g16 = l >> 4, l15 = l & 15;

  for (int which = 0; which < 2; ++which) {
    const float* src = which ? human : feats;
    us* dst = which ? xh : xf;
    for (int i = 0; i < 16; ++i) {
      int e = (i * 256 + t) * 4;
      int c = e >> 6, nn = e & 63;
      f32x4 v = *(const f32x4*)(src + (size_t)(b * CIN + c) * NN + n0 + nn);
#pragma unroll
      for (int j = 0; j < 4; ++j) {
        int row = nn + j;
        dst[row * 256 + (c ^ ((row & 15) << 3))] = f2bf(v[j]);
      }
    }
  }
  __syncthreads();

  const float* pb[4] = {hth_b, hph_b, th_b, ph_b};
  us* pout[4] = {hqT, hkT, thT, phT};

  // Transposed projections: M = n (rows), N = ci, K = c
  u32x4 afrag[8];
  const int arow = w * 16 + l15;
  for (int p = 0; p < 4; ++p) {
    const us* tile = (p < 2) ? xh : xf;
    if (p == 0 || p == 2) {
#pragma unroll
      for (int s = 0; s < 8; ++s)
        afrag[s] = *(const u32x4*)((const char*)tile + arow * 512 +
                                   (((s << 6) | (g16 << 4)) ^ (l15 << 4)));
    }
    const us* wbp = wb + p * 32768;
    for (int nt = 0; nt < 8; ++nt) {
      f32x4 acc = {0.f, 0.f, 0.f, 0.f};
#pragma unroll
      for (int s = 0; s < 8; ++s) {
        u32x4 bf = *(const u32x4*)(wbp + (nt * 16 + l15) * 256 + s * 32 + g16 * 8);
        acc = mfma16(afrag[s], bf, acc);
      }
      float bias = pb[p][nt * 16 + l15];
#pragma unroll
      for (int r = 0; r < 4; ++r) {
        int nrow = n0 + w * 16 + g16 * 4 + r;
        pout[p][((size_t)b * NN + nrow) * CI_ + nt * 16 + l15] = f2bf(acc[r] + bias);
      }
    }
  }

  // g projection: M = ci, N = n, K = c  (B-frags from xf LDS tile)
  const us* wbg = wb + 4 * 32768;
  u32x4 ag[2][8];
#pragma unroll
  for (int mt = 0; mt < 2; ++mt)
#pragma unroll
    for (int s = 0; s < 8; ++s)
      ag[mt][s] = *(const u32x4*)(wbg + (w * 32 + mt * 16 + l15) * 256 + s * 32 + g16 * 8);
  float gb[2][4];
#pragma unroll
  for (int mt = 0; mt < 2; ++mt)
#pragma unroll
    for (int r = 0; r < 4; ++r) gb[mt][r] = g_b[w * 32 + mt * 16 + g16 * 4 + r];
  for (int nt = 0; nt < 4; ++nt) {
    f32x4 acc0 = {0.f, 0.f, 0.f, 0.f}, acc1 = {0.f, 0.f, 0.f, 0.f};
#pragma unroll
    for (int s = 0; s < 8; ++s) {
      u32x4 bf = *(const u32x4*)((const char*)xf + (nt * 16 + l15) * 512 +
                                 ((s * 64 + g16 * 16) ^ (l15 << 4)));
      acc0 = mfma16(ag[0][s], bf, acc0);
      acc1 = mfma16(ag[1][s], bf, acc1);
    }
#pragma unroll
    for (int r = 0; r < 4; ++r) {
      int ci0 = w * 32 + g16 * 4 + r;
      gP[((size_t)b * CI_ + ci0) * NN + n0 + nt * 16 + l15] = f2bf(acc0[r] + gb[0][r]);
      gP[((size_t)b * CI_ + ci0 + 16) * NN + n0 + nt * 16 + l15] = f2bf(acc1[r] + gb[1][r]);
    }
  }
}

// ---------------- Kernel B: dual-path flash attention, K-split x path-split ----
// grid 1024 = 8 (xcd: b,path) x 2 (K-half) x 64 (q-chunk); 128 threads (2 waves)
// Each wave: 32 q rows (2 subtiles of 16), KVBLK=32, double-buffered staging.
__global__ __launch_bounds__(128, 2) void attn_kernel(
    const us* __restrict__ hqT, const us* __restrict__ hkT,
    const us* __restrict__ thT, const us* __restrict__ phT,
    const us* __restrict__ gP, us* __restrict__ PY, float* __restrict__ PL) {
  __shared__ alignas(16) us sK[2][32 * 128];   // [key][d], byte swz ((key&7)<<4)
  __shared__ alignas(16) us sV[2][64 * 64];    // pair-rows: [dd>>1][ (dd&1)*64 + 2k ], swz ((j&7)<<4)
  __shared__ alignas(16) us sPp[2][16 * 64];   // per-wave: [q>>1][ (q&1)*64 + 2k ], swz ((jp&7)<<4)
  const int t = threadIdx.x, w = t >> 6, l = t & 63, g16 = l >> 4, l15 = l & 15;
  const int id = blockIdx.x;
  const int xcd = id & 7, b = xcd & 3, path = xcd >> 2;
  const int r2 = id >> 3, h = r2 & 1, chunk = r2 >> 1;
  const int q0 = chunk * 64, kb = h * 2048;
  const us* Qsrc = path ? thT : hqT;
  const char* Kb = (const char*)(path ? phT : hkT) + (size_t)b * NN * 256;
  const char* Vb = (const char*)gP + (size_t)b * CI_ * NN * 2;

  u32x4 aQ[2][4];
#pragma unroll
  for (int qs = 0; qs < 2; ++qs)
#pragma unroll
    for (int s = 0; s < 4; ++s)
      aQ[qs][s] = *(const u32x4*)(Qsrc +
          ((size_t)b * NN + q0 + w * 32 + qs * 16 + l15) * CI_ + s * 32 + g16 * 8);

  f32x4 Y[2][8];
#pragma unroll
  for (int qs = 0; qs < 2; ++qs)
#pragma unroll
    for (int dt = 0; dt < 8; ++dt) Y[qs][dt] = {0.f, 0.f, 0.f, 0.f};
  float lsum[2] = {0.f, 0.f};

  auto stage = [&](int k0, int buf) {
#pragma unroll
    for (int i = 0; i < 4; ++i) {
      int krow = w * 16 + i * 4 + (l >> 4);
      gload16(Kb + (size_t)(k0 + krow) * 256 + (((l & 15) * 16) ^ ((krow & 7) << 4)),
              (char*)sK[buf] + (w * 16 + i * 4) * 256);
    }
#pragma unroll
    for (int i = 0; i < 4; ++i) {
      int j = w * 32 + i * 8 + (l >> 3);
      int srcin = ((l & 7) * 16) ^ ((j & 7) << 4);
      gload16(Vb + (size_t)(2 * j + (srcin >> 6)) * (NN * 2) + (size_t)k0 * 2 + (srcin & 63),
              (char*)sV[buf] + (w * 32 + i * 8) * 128);
    }
  };

  stage(kb, 0);
  __syncthreads();
  for (int kt = 0; kt < 64; ++kt) {
    const int cur = kt & 1;
    if (kt < 63) stage(kb + (kt + 1) * 32, cur ^ 1);
    const char* sKc = (const char*)sK[cur];
    const char* sVc = (const char*)sV[cur];
    // swapped QK^T: mfma(A=K, B=Q) -> lane holds P[q=l15][key=nt*16+g16*4+r]
    float pv[2][2][4];
#pragma unroll
    for (int nt = 0; nt < 2; ++nt) {
      f32x4 a0 = {0.f, 0.f, 0.f, 0.f}, a1 = {0.f, 0.f, 0.f, 0.f};
#pragma unroll
      for (int s = 0; s < 4; ++s) {
        u32x4 bk = *(const u32x4*)(sKc + (nt * 16 + l15) * 256 +
                                   ((s * 64 + g16 * 16) ^ ((l15 & 7) << 4)));
        a0 = mfma16(bk, aQ[0][s], a0);
        a1 = mfma16(bk, aQ[1][s], a1);
      }
#pragma unroll
      for (int r = 0; r < 4; ++r) {
        float p0 = __expf(a0[r] * SCALE), p1 = __expf(a1[r] * SCALE);
        lsum[0] += p0;
        lsum[1] += p1;
        pv[0][nt][r] = p0;
        pv[1][nt][r] = p1;
      }
    }
    // packed P writes: key k at linear (q&1)*64 + 2k within pair-row q>>1
#pragma unroll
    for (int qs = 0; qs < 2; ++qs)
#pragma unroll
      for (int nt = 0; nt < 2; ++nt) {
        u32x2 pw;
        pw[0] = pack2(pv[qs][nt][0], pv[qs][nt][1]);
        pw[1] = pack2(pv[qs][nt][2], pv[qs][nt][3]);
        *(u32x2*)((char*)sPp[w] + (qs * 8 + (l15 >> 1)) * 128 +
                  (((l15 & 1) * 64 + nt * 32 + g16 * 8) ^ ((l15 >> 1) << 4))) = pw;
      }
    u32x4 aP[2];
#pragma unroll
    for (int qs = 0; qs < 2; ++qs)
      aP[qs] = *(const u32x4*)((char*)sPp[w] + (qs * 8 + (l15 >> 1)) * 128 +
                               (((l15 & 1) * 64 + g16 * 16) ^ ((l15 >> 1) << 4)));
#pragma unroll
    for (int dt = 0; dt < 8; ++dt) {
      int dd = dt * 16 + l15;
      u32x4 bv = *(const u32x4*)(sVc + (dd >> 1) * 128 +
                                 (((dd & 1) * 64 + g16 * 16) ^ (((dd >> 1) & 7) << 4)));
      Y[0][dt] = mfma16(aP[0], bv, Y[0][dt]);
      Y[1][dt] = mfma16(aP[1], bv, Y[1][dt]);
    }
    __syncthreads();
  }

  const int bp = b * 2 + path;
#pragma unroll
  for (int qs = 0; qs < 2; ++qs) {
    float v = lsum[qs];
    v += __shfl_xor(v, 16);
    v += __shfl_xor(v, 32);
    if (g16 == 0)
      PL[(size_t)(h * 8 + bp) * NN + q0 + w * 32 + qs * 16 + l15] = v;
#pragma unroll
    for (int dt = 0; dt < 8; ++dt)
#pragma unroll
      for (int r = 0; r < 4; ++r)
        PY[(size_t)(h * 8 + bp) * (NN * CI_) +
           (size_t)(q0 + w * 32 + qs * 16 + g16 * 4 + r) * CI_ + dt * 16 + l15] =
            f2bf(Y[qs][dt][r]);
  }
}

// ---------------- Kernel C: combine + W conv + BN ----------------
__global__ __launch_bounds__(256) void wout_kernel(
    const us* __restrict__ PY, const float* __restrict__ PL,
    const us* __restrict__ wb, const float* __restrict__ Wb,
    const float* __restrict__ gamma, const float* __restrict__ beta,
    const float* __restrict__ mean, const float* __restrict__ var,
    float* __restrict__ out) {
  __shared__ alignas(16) us sY[64 * 128];  // [n][ci], byte swz ((n&7)<<4)
  const int t = threadIdx.x, w = t >> 6, l = t & 63, g16 = l >> 4, l15 = l & 15;
  const int n0 = blockIdx.x * 64;
  const int ob = blockIdx.y * 64;
  const int b = blockIdx.z;

  // ---- combine halves, normalize, average paths -> bf16 LDS tile
  {
    const int row = t >> 2, cg = t & 3;
    const int n = n0 + row;
    float ls[2];
#pragma unroll
    for (int p = 0; p < 2; ++p) {
      int bpi = b * 2 + p;
      ls[p] = 0.5f / (PL[(size_t)bpi * NN + n] + PL[(size_t)(8 + bpi) * NN + n]);
    }
    float acc[32];
#pragma unroll
    for (int e = 0; e < 32; ++e) acc[e] = 0.f;
#pragma unroll
    for (int p = 0; p < 2; ++p) {
      float sc = ls[p];
#pragma unroll
      for (int hh = 0; hh < 2; ++hh) {
        const us* src = PY + (size_t)(hh * 8 + b * 2 + p) * (NN * CI_) +
                        (size_t)n * CI_ + cg * 32;
#pragma unroll
        for (int j = 0; j < 4; ++j) {
          u32x4 v = *(const u32x4*)(src + j * 8);
#pragma unroll
          for (int e = 0; e < 4; ++e) {
            unsigned u = v[e];
            acc[j * 8 + 2 * e] += __uint_as_float(u << 16) * sc;
            acc[j * 8 + 2 * e + 1] += __uint_as_float(u & 0xFFFF0000u) * sc;
          }
        }
      }
    }
#pragma unroll
    for (int j = 0; j < 4; ++j) {
      u32x4 o;
#pragma unroll
      for (int e = 0; e < 4; ++e)
        o[e] = pack2(acc[j * 8 + 2 * e], acc[j * 8 + 2 * e + 1]);
      *(u32x4*)((char*)sY + row * 256 + ((cg * 64 + j * 16) ^ ((row & 7) << 4))) = o;
    }
  }

  const us* wbw = wb + 5 * 32768;
  u32x4 aW[4];
  const int orow = ob + w * 16 + l15;
#pragma unroll
  for (int s = 0; s < 4; ++s)
    aW[s] = *(const u32x4*)(wbw + orow * 128 + s * 32 + g16 * 8);
  float wbias[4], inv_[4], mu[4], bt[4];
#pragma unroll
  for (int r = 0; r < 4; ++r) {
    int o = ob + w * 16 + g16 * 4 + r;
    wbias[r] = Wb[o];
    inv_[r] = gamma[o] * rsqrtf(var[o] + 1e-5f);
    mu[r] = mean[o];
    bt[r] = beta[o];
  }
  __syncthreads();

  for (int nt = 0; nt < 4; ++nt) {
    f32x4 acc = {0.f, 0.f, 0.f, 0.f};
#pragma unroll
    for (int s = 0; s < 4; ++s) {
      u32x4 bf = *(const u32x4*)((const char*)sY + (nt * 16 + l15) * 256 +
                                 (((s << 6) | (g16 << 4)) ^ ((l15 & 7) << 4)));
      acc = mfma16(aW[s], bf, acc);
    }
#pragma unroll
    for (int r = 0; r < 4; ++r) {
      int o = ob + w * 16 + g16 * 4 + r;
      out[((size_t)b * CIN + o) * NN + n0 + nt * 16 + l15] =
          (acc[r] + wbias[r] - mu[r]) * inv_[r] + bt[r];
    }
  }
}

extern "C" void kernel_launch(void* const* d_in, const int* in_sizes, int n_in,
                              void* d_out, int out_size, void* d_ws, size_t ws_size,
                              hipStream_t stream) {
  const float* feats = (const float*)d_in[0];
  const float* human = (const float*)d_in[1];
  const float* g_w = (const float*)d_in[2];
  const float* g_b = (const float*)d_in[3];
  const float* th_w = (const float*)d_in[4];
  const float* th_b = (const float*)d_in[5];
  const float* ph_w = (const float*)d_in[6];
  const float* ph_b = (const float*)d_in[7];
  const float* hth_w = (const float*)d_in[8];
  const float* hth_b = (const float*)d_in[9];
  const float* hph_w = (const float*)d_in[10];
  const float* hph_b = (const float*)d_in[11];
  const float* Ww = (const float*)d_in[12];
  const float* Wb = (const float*)d_in[13];
  const float* gamma = (const float*)d_in[14];
  const float* beta = (const float*)d_in[15];
  const float* mean = (const float*)d_in[16];
  const float* var = (const float*)d_in[17];

  us* ws = (us*)d_ws;
  const size_t SZ = (size_t)NB * NN * CI_;  // 2,097,152 elems per projection
  us* hqT = ws;
  us* hkT = ws + SZ;
  us* thT = ws + 2 * SZ;
  us* phT = ws + 3 * SZ;
  us* gP = ws + 4 * SZ;
  us* PY = ws + 5 * SZ;                       // 16 * NN * CI_ bf16 = 8,388,608 us
  float* PL = (float*)(ws + 5 * SZ + 8388608);  // 16*NN f32
  us* wb = ws + 5 * SZ + 8388608 + 131072;      // 6*32768 bf16

  wcvt_kernel<<<dim3(32, 6), 256, 0, stream>>>(hth_w, hph_w, th_w, ph_w, g_w, Ww, wb);
  proj_kernel<<<dim3(64, 4), 256, 0, stream>>>(feats, human, g_b, th_b, ph_b,
                                               hth_b, hph_b, wb, hqT, hkT, thT,
                                               phT, gP);
  attn_kernel<<<1024, 128, 0, stream>>>(hqT, hkT, thT, phT, gP, PY, PL);
  wout_kernel<<<dim3(64, 4, 4), 256, 0, stream>>>(PY, PL, wb, Wb, gamma, beta,
                                                  mean, var, (float*)d_out);
}